// Round 1
// baseline (7612.341 us; speedup 1.0000x reference)
//
#include <hip/hip_runtime.h>
#include <hip/hip_bf16.h>
#include <stdint.h>
#include <stddef.h>

#define NN 100000      // nodes
#define NE 256000      // edges
#define EMBD 300
#define C1D 600        // 2*EMB
#define NL 5
#define BNEPS 1e-5f

__device__ __forceinline__ float bf2f(unsigned short u) {
  unsigned int x = ((unsigned int)u) << 16;
  return __uint_as_float(x);
}
__device__ __forceinline__ unsigned short f2bf(float f) {
  unsigned int x = __float_as_uint(f);
  unsigned int r = x + 0x7fffu + ((x >> 16) & 1u);   // round-to-nearest-even
  return (unsigned short)(r >> 16);
}

// ---------------- small utility kernels ----------------

__global__ void zero_stats_k(float* __restrict__ stats) {
  for (int i = threadIdx.x; i < 3600; i += blockDim.x) stats[i] = 0.0f;
}

// agg = (1+eps[l]) * h      (vectorized float4; 300 % 4 == 0)
__global__ void init_agg_k(const float* __restrict__ h, const float* __restrict__ eps,
                           int l, float* __restrict__ agg) {
  float s = 1.0f + eps[l];
  int i = blockIdx.x * blockDim.x + threadIdx.x;
  const int n4 = NN * (EMBD / 4);
  if (i >= n4) return;
  float4 v = ((const float4*)h)[i];
  v.x *= s; v.y *= s; v.z *= s; v.w *= s;
  ((float4*)agg)[i] = v;
}

// one wave per edge: msg = relu(h[src] + tab[ea0] + tab[6+ea1]); atomicAdd into agg[dst]
__global__ void edge_scatter_k(const float* __restrict__ h, const float* __restrict__ Wb_l,
                               const int* __restrict__ ei, const int* __restrict__ ea,
                               float* __restrict__ agg) {
  __shared__ float tab[EMBD * 9];
  for (int i = threadIdx.x; i < EMBD * 9; i += blockDim.x) tab[i] = Wb_l[i];
  __syncthreads();
  int wave = threadIdx.x >> 6;
  int lane = threadIdx.x & 63;
  int e = blockIdx.x * 4 + wave;
  if (e >= NE) return;
  int src = ei[e];
  int dst = ei[NE + e];
  int t0 = ea[2 * e];
  int t1 = ea[2 * e + 1] + 6;
  const float* hs = h + (size_t)src * EMBD;
  float* ad = agg + (size_t)dst * EMBD;
  for (int d = lane; d < EMBD; d += 64) {
    float m = hs[d] + tab[d * 9 + t0] + tab[d * 9 + t1];
    if (m > 0.0f) atomicAdd(&ad[d], m);   // relu: zero contribution -> skip atomic
  }
}

// scale/shift from accumulated sums
__global__ void finalize_k(const float* __restrict__ sum, const float* __restrict__ sq,
                           const float* __restrict__ g, const float* __restrict__ b,
                           float* __restrict__ scale, float* __restrict__ shift, int C) {
  int j = blockIdx.x * blockDim.x + threadIdx.x;
  if (j >= C) return;
  float mean = sum[j] * (1.0f / NN);
  float var = sq[j] * (1.0f / NN) - mean * mean;
  float sc = g[j] * rsqrtf(var + BNEPS);
  scale[j] = sc;
  shift[j] = b[j] - mean * sc;
}

// h = bn2(z2) (+relu for l<4)
__global__ void bn_apply_k(const float* __restrict__ z2, const float* __restrict__ scale,
                           const float* __restrict__ shift, int do_relu, float* __restrict__ out) {
  int i = blockIdx.x * blockDim.x + threadIdx.x;
  const int n4 = NN * (EMBD / 4);
  if (i >= n4) return;
  int c4 = (i % (EMBD / 4)) * 4;
  float4 v = ((const float4*)z2)[i];
  float4 sc = *(const float4*)(scale + c4);
  float4 sh = *(const float4*)(shift + c4);
  v.x = v.x * sc.x + sh.x;
  v.y = v.y * sc.y + sh.y;
  v.z = v.z * sc.z + sh.z;
  v.w = v.w * sc.w + sh.w;
  if (do_relu) {
    v.x = fmaxf(v.x, 0.0f); v.y = fmaxf(v.y, 0.0f);
    v.z = fmaxf(v.z, 0.0f); v.w = fmaxf(v.w, 0.0f);
  }
  ((float4*)out)[i] = v;
}

// ---------------- GEMM1: z1 = agg(M x 300) @ W1^T(300 x 600) + b1 ; store bf16; col stats ----------------
// 128x128 tile, BK=8, 256 threads, 8x8 micro-tile.

#define BM 128
#define BN 128
#define BK 8

__global__ __launch_bounds__(256) void gemm1_k(
    const float* __restrict__ A,        // M x 300
    const float* __restrict__ W,        // 600 x 300 (row-major), use W[n*300+k]
    const float* __restrict__ bias,     // 600
    unsigned short* __restrict__ Z1,    // M x 600 bf16
    float* __restrict__ sumb, float* __restrict__ sqb) {
  const int M = NN, K = EMBD, NC = C1D;
  __shared__ float As[BK][BM];
  __shared__ float Bs[BK][BN];
  __shared__ float red[16][BN];

  int tid = threadIdx.x;
  int tx = tid & 15, ty = tid >> 4;
  int m0 = blockIdx.x * BM, n0 = blockIdx.y * BN;
  int lm = tid >> 1;            // 0..127
  int lk = (tid & 1) * 4;       // 0 or 4

  float acc[8][8] = {};

  for (int k0 = 0; k0 < K; k0 += BK) {
    // A tile
    {
      int m = m0 + lm, k = k0 + lk;
      float4 v = make_float4(0, 0, 0, 0);
      if (m < M) {
        if (k + 3 < K) v = *(const float4*)(A + (size_t)m * K + k);
        else {
          float* vv = &v.x;
          for (int j = 0; j < 4; ++j) { int kk = k + j; vv[j] = (kk < K) ? A[(size_t)m * K + kk] : 0.0f; }
        }
      }
      As[lk + 0][lm] = v.x; As[lk + 1][lm] = v.y; As[lk + 2][lm] = v.z; As[lk + 3][lm] = v.w;
    }
    // B tile: Bs[kk][n] = W[(n0+n)*K + k0+kk]
    {
      int n = n0 + lm, k = k0 + lk;
      float4 v = make_float4(0, 0, 0, 0);
      if (n < NC) {
        if (k + 3 < K) v = *(const float4*)(W + (size_t)n * K + k);
        else {
          float* vv = &v.x;
          for (int j = 0; j < 4; ++j) { int kk = k + j; vv[j] = (kk < K) ? W[(size_t)n * K + kk] : 0.0f; }
        }
      }
      Bs[lk + 0][lm] = v.x; Bs[lk + 1][lm] = v.y; Bs[lk + 2][lm] = v.z; Bs[lk + 3][lm] = v.w;
    }
    __syncthreads();
#pragma unroll
    for (int kk = 0; kk < BK; ++kk) {
      float a[8], b[8];
      *(float4*)&a[0] = *(const float4*)&As[kk][ty * 8];
      *(float4*)&a[4] = *(const float4*)&As[kk][ty * 8 + 4];
      *(float4*)&b[0] = *(const float4*)&Bs[kk][tx * 8];
      *(float4*)&b[4] = *(const float4*)&Bs[kk][tx * 8 + 4];
#pragma unroll
      for (int i = 0; i < 8; ++i)
#pragma unroll
        for (int j = 0; j < 8; ++j) acc[i][j] += a[i] * b[j];
    }
    __syncthreads();
  }

  // epilogue: bias, bf16 store, per-column stats
  int cbase = n0 + tx * 8;                  // 600 % 8 == 0 -> group fully valid or fully invalid
  bool cval = (cbase + 7) < NC;
  float bsv[8];
#pragma unroll
  for (int j = 0; j < 8; ++j) bsv[j] = cval ? bias[cbase + j] : 0.0f;
  float csum[8] = {}, csq[8] = {};
#pragma unroll
  for (int i = 0; i < 8; ++i) {
    int m = m0 + ty * 8 + i;
    if (m < M && cval) {
      unsigned short us[8];
#pragma unroll
      for (int j = 0; j < 8; ++j) {
        float v = acc[i][j] + bsv[j];
        us[j] = f2bf(v);
        csum[j] += v; csq[j] += v * v;
      }
      *(float4*)(Z1 + (size_t)m * NC + cbase) = *(float4*)us;   // 8 bf16 = 16B
    }
  }
  __syncthreads();
#pragma unroll
  for (int j = 0; j < 8; ++j) red[ty][tx * 8 + j] = csum[j];
  __syncthreads();
  if (tid < BN) {
    float s = 0;
#pragma unroll
    for (int t = 0; t < 16; ++t) s += red[t][tid];
    int c = n0 + tid;
    if (c < NC) atomicAdd(&sumb[c], s);
  }
  __syncthreads();
#pragma unroll
  for (int j = 0; j < 8; ++j) red[ty][tx * 8 + j] = csq[j];
  __syncthreads();
  if (tid < BN) {
    float s = 0;
#pragma unroll
    for (int t = 0; t < 16; ++t) s += red[t][tid];
    int c = n0 + tid;
    if (c < NC) atomicAdd(&sqb[c], s);
  }
}

// ---------------- GEMM2: z2 = relu(bn1(z1))(M x 600) @ W2^T(600 x 300) + b2 ; f32 out; col stats ----------------

__global__ __launch_bounds__(256) void gemm2_k(
    const unsigned short* __restrict__ Z1,   // M x 600 bf16 (raw, pre-BN)
    const float* __restrict__ scale1, const float* __restrict__ shift1,  // 600
    const float* __restrict__ W,        // 300 x 600 (row-major), use W[n*600+k]
    const float* __restrict__ bias,     // 300
    float* __restrict__ Z2,             // M x 300 f32
    float* __restrict__ sumb, float* __restrict__ sqb) {
  const int M = NN, K = C1D, NC = EMBD;
  __shared__ float As[BK][BM];
  __shared__ float Bs[BK][BN];
  __shared__ float red[16][BN];

  int tid = threadIdx.x;
  int tx = tid & 15, ty = tid >> 4;
  int m0 = blockIdx.x * BM, n0 = blockIdx.y * BN;
  int lm = tid >> 1;
  int lk = (tid & 1) * 4;

  float acc[8][8] = {};

  for (int k0 = 0; k0 < K; k0 += BK) {     // 600/8 = 75 exact
    // A tile with fused BN1 + relu
    {
      int m = m0 + lm, k = k0 + lk;
      float4 v = make_float4(0, 0, 0, 0);
      if (m < M) {
        ushort4 u = *(const ushort4*)(Z1 + (size_t)m * K + k);
        float4 sc = *(const float4*)(scale1 + k);
        float4 sh = *(const float4*)(shift1 + k);
        v.x = fmaxf(bf2f(u.x) * sc.x + sh.x, 0.0f);
        v.y = fmaxf(bf2f(u.y) * sc.y + sh.y, 0.0f);
        v.z = fmaxf(bf2f(u.z) * sc.z + sh.z, 0.0f);
        v.w = fmaxf(bf2f(u.w) * sc.w + sh.w, 0.0f);
      }
      As[lk + 0][lm] = v.x; As[lk + 1][lm] = v.y; As[lk + 2][lm] = v.z; As[lk + 3][lm] = v.w;
    }
    // B tile
    {
      int n = n0 + lm, k = k0 + lk;
      float4 v = make_float4(0, 0, 0, 0);
      if (n < NC) v = *(const float4*)(W + (size_t)n * K + k);
      Bs[lk + 0][lm] = v.x; Bs[lk + 1][lm] = v.y; Bs[lk + 2][lm] = v.z; Bs[lk + 3][lm] = v.w;
    }
    __syncthreads();
#pragma unroll
    for (int kk = 0; kk < BK; ++kk) {
      float a[8], b[8];
      *(float4*)&a[0] = *(const float4*)&As[kk][ty * 8];
      *(float4*)&a[4] = *(const float4*)&As[kk][ty * 8 + 4];
      *(float4*)&b[0] = *(const float4*)&Bs[kk][tx * 8];
      *(float4*)&b[4] = *(const float4*)&Bs[kk][tx * 8 + 4];
#pragma unroll
      for (int i = 0; i < 8; ++i)
#pragma unroll
        for (int j = 0; j < 8; ++j) acc[i][j] += a[i] * b[j];
    }
    __syncthreads();
  }

  // epilogue: bias, f32 store, per-column stats (NC=300, 300 % 8 != 0 -> per-element col guard)
  float csum[8] = {}, csq[8] = {};
#pragma unroll
  for (int i = 0; i < 8; ++i) {
    int m = m0 + ty * 8 + i;
    if (m < M) {
#pragma unroll
      for (int j = 0; j < 8; ++j) {
        int c = n0 + tx * 8 + j;
        if (c < NC) {
          float v = acc[i][j] + bias[c];
          Z2[(size_t)m * NC + c] = v;
          csum[j] += v; csq[j] += v * v;
        }
      }
    }
  }
  __syncthreads();
#pragma unroll
  for (int j = 0; j < 8; ++j) red[ty][tx * 8 + j] = csum[j];
  __syncthreads();
  if (tid < BN) {
    float s = 0;
#pragma unroll
    for (int t = 0; t < 16; ++t) s += red[t][tid];
    int c = n0 + tid;
    if (c < NC) atomicAdd(&sumb[c], s);
  }
  __syncthreads();
#pragma unroll
  for (int j = 0; j < 8; ++j) red[ty][tx * 8 + j] = csq[j];
  __syncthreads();
  if (tid < BN) {
    float s = 0;
#pragma unroll
    for (int t = 0; t < 16; ++t) s += red[t][tid];
    int c = n0 + tid;
    if (c < NC) atomicAdd(&sqb[c], s);
  }
}

// ---------------- host ----------------

extern "C" void kernel_launch(void* const* d_in, const int* in_sizes, int n_in,
                              void* d_out, int out_size, void* d_ws, size_t ws_size,
                              hipStream_t stream) {
  const float* x    = (const float*)d_in[0];
  const float* Wb   = (const float*)d_in[1];   // (L, 300, 9)
  const float* eps  = (const float*)d_in[2];   // (L,)
  const float* W1   = (const float*)d_in[3];   // (L, 600, 300)
  const float* b1   = (const float*)d_in[4];   // (L, 600)
  const float* bn1g = (const float*)d_in[5];
  const float* bn1b = (const float*)d_in[6];
  const float* W2   = (const float*)d_in[7];   // (L, 300, 600)
  const float* b2   = (const float*)d_in[8];   // (L, 300)
  const float* bng  = (const float*)d_in[9];
  const float* bnb  = (const float*)d_in[10];
  const int*   ei   = (const int*)d_in[11];    // (2, E)
  const int*   ea   = (const int*)d_in[12];    // (E, 2)

  float* h = (float*)d_out;                       // N x 300 f32 (also aliases z1 bf16 region)
  unsigned short* z1 = (unsigned short*)d_out;    // N x 600 bf16 == exactly out bytes
  float* agg = (float*)d_ws;                      // N x 300 f32 (also reused as z2)
  float* z2 = agg;
  float* stats = (float*)d_ws + (size_t)NN * EMBD;
  // stats layout: [0,600) sum1 | [600,1200) sq1 | [1200,1800) scale1 | [1800,2400) shift1
  //               [2400,2700) sum2 | [2700,3000) sq2 | [3000,3300) scale2 | [3300,3600) shift2

  // h = x
  hipMemcpyAsync(h, x, (size_t)NN * EMBD * sizeof(float), hipMemcpyDeviceToDevice, stream);

  const int n4 = NN * (EMBD / 4);
  const int eltGrid = (n4 + 255) / 256;

  for (int l = 0; l < NL; ++l) {
    zero_stats_k<<<1, 1024, 0, stream>>>(stats);
    init_agg_k<<<eltGrid, 256, 0, stream>>>(h, eps, l, agg);
    edge_scatter_k<<<NE / 4, 256, 0, stream>>>(h, Wb + (size_t)l * EMBD * 9, ei, ea, agg);
    gemm1_k<<<dim3((NN + BM - 1) / BM, (C1D + BN - 1) / BN), 256, 0, stream>>>(
        agg, W1 + (size_t)l * C1D * EMBD, b1 + (size_t)l * C1D, z1, stats + 0, stats + 600);
    finalize_k<<<3, 256, 0, stream>>>(stats + 0, stats + 600, bn1g + (size_t)l * C1D,
                                      bn1b + (size_t)l * C1D, stats + 1200, stats + 1800, C1D);
    gemm2_k<<<dim3((NN + BM - 1) / BM, (EMBD + BN - 1) / BN), 256, 0, stream>>>(
        z1, stats + 1200, stats + 1800, W2 + (size_t)l * EMBD * C1D, b2 + (size_t)l * EMBD,
        z2, stats + 2400, stats + 2700);
    finalize_k<<<2, 256, 0, stream>>>(stats + 2400, stats + 2700, bng + (size_t)l * EMBD,
                                      bnb + (size_t)l * EMBD, stats + 3000, stats + 3300, EMBD);
    bn_apply_k<<<eltGrid, 256, 0, stream>>>(z2, stats + 3000, stats + 3300, (l < NL - 1) ? 1 : 0, h);
  }
}

// Round 2
// 6409.337 us; speedup vs baseline: 1.1877x; 1.1877x over previous
//
#include <hip/hip_runtime.h>
#include <hip/hip_bf16.h>
#include <stdint.h>
#include <stddef.h>
#include <string.h>

#define NN 100000      // nodes
#define NE 256000      // edges
#define EMBD 300
#define C1D 600        // 2*EMB
#define NL 5
#define BNEPS 1e-5f

typedef short bf16x8 __attribute__((ext_vector_type(8)));
typedef float f32x4 __attribute__((ext_vector_type(4)));

__device__ __forceinline__ float bf2f(unsigned short u) {
  unsigned int x = ((unsigned int)u) << 16;
  return __uint_as_float(x);
}
__device__ __forceinline__ unsigned short f2bf(float f) {
  unsigned int x = __float_as_uint(f);
  unsigned int r = x + 0x7fffu + ((x >> 16) & 1u);   // round-to-nearest-even
  return (unsigned short)(r >> 16);
}

// split (a,b) into packed bf16 hi (RNE) and packed bf16 lo (residual)
__device__ __forceinline__ void split2(float a, float b, unsigned int& hi, unsigned int& lo) {
  float2 p = make_float2(a, b);
  __hip_bfloat162 hb = __float22bfloat162_rn(p);
  unsigned int hraw;
  memcpy(&hraw, &hb, 4);
  float2 hf = __bfloat1622float2(hb);
  float2 lf = make_float2(a - hf.x, b - hf.y);
  __hip_bfloat162 lb = __float22bfloat162_rn(lf);
  unsigned int lraw;
  memcpy(&lraw, &lb, 4);
  hi = hraw; lo = lraw;
}

// ---------------- small utility kernels ----------------

__global__ void zero_stats_k(float* __restrict__ stats) {
  for (int i = threadIdx.x; i < 3600; i += blockDim.x) stats[i] = 0.0f;
}

// agg = (1+eps[l]) * h      (vectorized float4; 300 % 4 == 0)
__global__ void init_agg_k(const float* __restrict__ h, const float* __restrict__ eps,
                           int l, float* __restrict__ agg) {
  float s = 1.0f + eps[l];
  int i = blockIdx.x * blockDim.x + threadIdx.x;
  const int n4 = NN * (EMBD / 4);
  if (i >= n4) return;
  float4 v = ((const float4*)h)[i];
  v.x *= s; v.y *= s; v.z *= s; v.w *= s;
  ((float4*)agg)[i] = v;
}

// one wave per edge: msg = relu(h[src] + tab[ea0] + tab[6+ea1]); atomicAdd into agg[dst]
__global__ void edge_scatter_k(const float* __restrict__ h, const float* __restrict__ Wb_l,
                               const int* __restrict__ ei, const int* __restrict__ ea,
                               float* __restrict__ agg) {
  __shared__ float tab[EMBD * 9];
  for (int i = threadIdx.x; i < EMBD * 9; i += blockDim.x) tab[i] = Wb_l[i];
  __syncthreads();
  int wave = threadIdx.x >> 6;
  int lane = threadIdx.x & 63;
  int e = blockIdx.x * 4 + wave;
  if (e >= NE) return;
  int src = ei[e];
  int dst = ei[NE + e];
  int t0 = ea[2 * e];
  int t1 = ea[2 * e + 1] + 6;
  const float* hs = h + (size_t)src * EMBD;
  float* ad = agg + (size_t)dst * EMBD;
  for (int d = lane; d < EMBD; d += 64) {
    float m = hs[d] + tab[d * 9 + t0] + tab[d * 9 + t1];
    if (m > 0.0f) atomicAdd(&ad[d], m);   // relu: zero contribution -> skip atomic
  }
}

// scale/shift from accumulated sums
__global__ void finalize_k(const float* __restrict__ sum, const float* __restrict__ sq,
                           const float* __restrict__ g, const float* __restrict__ b,
                           float* __restrict__ scale, float* __restrict__ shift, int C) {
  int j = blockIdx.x * blockDim.x + threadIdx.x;
  if (j >= C) return;
  float mean = sum[j] * (1.0f / NN);
  float var = sq[j] * (1.0f / NN) - mean * mean;
  float sc = g[j] * rsqrtf(var + BNEPS);
  scale[j] = sc;
  shift[j] = b[j] - mean * sc;
}

// h = bn2(z2) (+relu for l<4)
__global__ void bn_apply_k(const float* __restrict__ z2, const float* __restrict__ scale,
                           const float* __restrict__ shift, int do_relu, float* __restrict__ out) {
  int i = blockIdx.x * blockDim.x + threadIdx.x;
  const int n4 = NN * (EMBD / 4);
  if (i >= n4) return;
  int c4 = (i % (EMBD / 4)) * 4;
  float4 v = ((const float4*)z2)[i];
  float4 sc = *(const float4*)(scale + c4);
  float4 sh = *(const float4*)(shift + c4);
  v.x = v.x * sc.x + sh.x;
  v.y = v.y * sc.y + sh.y;
  v.z = v.z * sc.z + sh.z;
  v.w = v.w * sc.w + sh.w;
  if (do_relu) {
    v.x = fmaxf(v.x, 0.0f); v.y = fmaxf(v.y, 0.0f);
    v.z = fmaxf(v.z, 0.0f); v.w = fmaxf(v.w, 0.0f);
  }
  ((float4*)out)[i] = v;
}

// ---------------- MFMA GEMMs ----------------
// 128x128 tile, BK=32, 256 threads (4 waves, 2x2 of 64x64 wave-tiles).
// A and B split into bf16 hi/lo planes in LDS; 3-term MFMA:
//   acc += Ahi*Bhi + Alo*Bhi + Ahi*Blo   (~f32 accuracy)
// LDS row stride 40 bf16 (pad 32->40): b128 frag reads are 2-way bank aliased = free.

#define TM 128
#define TN 128
#define TK 32
#define LDT 40

// GEMM1: z1 = agg(M x 300) @ W1[l]^T  + b1 ; z1 stored bf16 (RNE); column stats accumulated.
__global__ __launch_bounds__(256, 2) void gemm1_mfma_k(
    const float* __restrict__ A,        // M x 300 f32
    const float* __restrict__ W,        // 600 x 300 f32 (n-major, k contiguous)
    const float* __restrict__ bias,     // 600
    unsigned short* __restrict__ Z1,    // M x 600 bf16
    float* __restrict__ sumb, float* __restrict__ sqb) {
  const int M = NN, K = EMBD, NC = C1D;
  __shared__ unsigned short Ah[TM * LDT], Al[TM * LDT];
  __shared__ unsigned short Bh[TN * LDT], Bl[TN * LDT];

  int tid = threadIdx.x;
  int m0 = blockIdx.x * TM, n0 = blockIdx.y * TN;
  int w = tid >> 6, lane = tid & 63;
  int wm = w & 1, wn = w >> 1;
  int lm16 = lane & 15, quad = lane >> 4;

  f32x4 acc[4][4] = {};

  for (int k0 = 0; k0 < K; k0 += TK) {
    // ---- stage A (f32 -> hi/lo bf16), 128 rows x 32 k = 1024 float4-units
#pragma unroll
    for (int i = 0; i < 4; ++i) {
      int u = tid + i * 256;
      int row = u >> 3, q = u & 7;
      int k = k0 + q * 4;
      int m = m0 + row;
      float4 v = make_float4(0, 0, 0, 0);
      if (m < M) {
        if (k + 3 < K) v = *(const float4*)(A + (size_t)m * K + k);
        else {
          float* vv = &v.x;
#pragma unroll
          for (int j = 0; j < 4; ++j) if (k + j < K) vv[j] = A[(size_t)m * K + k + j];
        }
      }
      unsigned int h0, l0, h1, l1;
      split2(v.x, v.y, h0, l0);
      split2(v.z, v.w, h1, l1);
      *(uint2*)&Ah[row * LDT + q * 4] = make_uint2(h0, h1);
      *(uint2*)&Al[row * LDT + q * 4] = make_uint2(l0, l1);
    }
    // ---- stage B (W rows are n, k contiguous)
#pragma unroll
    for (int i = 0; i < 4; ++i) {
      int u = tid + i * 256;
      int row = u >> 3, q = u & 7;
      int k = k0 + q * 4;
      int n = n0 + row;
      float4 v = make_float4(0, 0, 0, 0);
      if (n < NC) {
        if (k + 3 < K) v = *(const float4*)(W + (size_t)n * K + k);
        else {
          float* vv = &v.x;
#pragma unroll
          for (int j = 0; j < 4; ++j) if (k + j < K) vv[j] = W[(size_t)n * K + k + j];
        }
      }
      unsigned int h0, l0, h1, l1;
      split2(v.x, v.y, h0, l0);
      split2(v.z, v.w, h1, l1);
      *(uint2*)&Bh[row * LDT + q * 4] = make_uint2(h0, h1);
      *(uint2*)&Bl[row * LDT + q * 4] = make_uint2(l0, l1);
    }
    __syncthreads();

    bf16x8 ah[4], al[4], bh[4], bl[4];
#pragma unroll
    for (int t = 0; t < 4; ++t) {
      int ar = (wm * 64 + t * 16 + lm16) * LDT + quad * 8;
      ah[t] = *(const bf16x8*)&Ah[ar];
      al[t] = *(const bf16x8*)&Al[ar];
      int br = (wn * 64 + t * 16 + lm16) * LDT + quad * 8;
      bh[t] = *(const bf16x8*)&Bh[br];
      bl[t] = *(const bf16x8*)&Bl[br];
    }
#pragma unroll
    for (int mt = 0; mt < 4; ++mt)
#pragma unroll
      for (int nt = 0; nt < 4; ++nt) {
        acc[mt][nt] = __builtin_amdgcn_mfma_f32_16x16x32_bf16(ah[mt], bh[nt], acc[mt][nt], 0, 0, 0);
        acc[mt][nt] = __builtin_amdgcn_mfma_f32_16x16x32_bf16(al[mt], bh[nt], acc[mt][nt], 0, 0, 0);
        acc[mt][nt] = __builtin_amdgcn_mfma_f32_16x16x32_bf16(ah[mt], bl[nt], acc[mt][nt], 0, 0, 0);
      }
    __syncthreads();
  }

  // ---- epilogue: bias, bf16 store, column stats
  // C/D layout: col = lane&15 (within 16x16 tile), row = quad*4 + reg
#pragma unroll
  for (int nt = 0; nt < 4; ++nt) {
    int c = n0 + wn * 64 + nt * 16 + lm16;
    bool cv = c < NC;
    float bs = cv ? bias[c] : 0.0f;
    float csum = 0.0f, csq = 0.0f;
#pragma unroll
    for (int mt = 0; mt < 4; ++mt) {
      int rbase = m0 + wm * 64 + mt * 16 + quad * 4;
#pragma unroll
      for (int r = 0; r < 4; ++r) {
        int mm = rbase + r;
        if (mm < M && cv) {
          float v = acc[mt][nt][r] + bs;
          Z1[(size_t)mm * NC + c] = f2bf(v);
          csum += v; csq += v * v;
        }
      }
    }
    csum += __shfl_down(csum, 16); csum += __shfl_down(csum, 32);
    csq  += __shfl_down(csq, 16);  csq  += __shfl_down(csq, 32);
    if (quad == 0 && cv) {
      atomicAdd(&sumb[c], csum);
      atomicAdd(&sqb[c], csq);
    }
  }
}

// GEMM2: z2 = relu(bn1(z1))(M x 600) @ W2[l]^T + b2 ; f32 out; column stats.
__global__ __launch_bounds__(256, 2) void gemm2_mfma_k(
    const unsigned short* __restrict__ Z1,   // M x 600 bf16 (raw pre-BN)
    const float* __restrict__ scale1, const float* __restrict__ shift1,  // 600
    const float* __restrict__ W,        // 300 x 600 f32 (n-major, k contiguous)
    const float* __restrict__ bias,     // 300
    float* __restrict__ Z2,             // M x 300 f32
    float* __restrict__ sumb, float* __restrict__ sqb) {
  const int M = NN, K = C1D, NC = EMBD;
  __shared__ unsigned short Ah[TM * LDT], Al[TM * LDT];
  __shared__ unsigned short Bh[TN * LDT], Bl[TN * LDT];

  int tid = threadIdx.x;
  int m0 = blockIdx.x * TM, n0 = blockIdx.y * TN;
  int w = tid >> 6, lane = tid & 63;
  int wm = w & 1, wn = w >> 1;
  int lm16 = lane & 15, quad = lane >> 4;

  f32x4 acc[4][4] = {};

  for (int k0 = 0; k0 < K; k0 += TK) {   // 19 steps (608 padded)
    // ---- stage A: z1 bf16 -> bn1+relu (f32) -> hi/lo split. 128 rows x 4 groups of 8
#pragma unroll
    for (int i = 0; i < 2; ++i) {
      int u = tid + i * 256;            // 0..511
      int row = u >> 2, g = u & 3;
      int k = k0 + g * 8;
      int m = m0 + row;
      float vals[8];
#pragma unroll
      for (int j = 0; j < 8; ++j) vals[j] = 0.0f;
      if (m < M) {
        if (k + 7 < K) {
          union { uint4 u4; unsigned short us[8]; } rr;
          rr.u4 = *(const uint4*)(Z1 + (size_t)m * K + k);
          float4 sc0 = *(const float4*)(scale1 + k);
          float4 sc1 = *(const float4*)(scale1 + k + 4);
          float4 sh0 = *(const float4*)(shift1 + k);
          float4 sh1 = *(const float4*)(shift1 + k + 4);
          const float* scp = &sc0.x; const float* shp = &sh0.x;
          const float* scq = &sc1.x; const float* shq = &sh1.x;
#pragma unroll
          for (int j = 0; j < 4; ++j) {
            vals[j]     = fmaxf(bf2f(rr.us[j])     * scp[j] + shp[j], 0.0f);
            vals[j + 4] = fmaxf(bf2f(rr.us[j + 4]) * scq[j] + shq[j], 0.0f);
          }
        } else {
#pragma unroll
          for (int j = 0; j < 8; ++j) {
            int kk = k + j;
            if (kk < K)
              vals[j] = fmaxf(bf2f(Z1[(size_t)m * K + kk]) * scale1[kk] + shift1[kk], 0.0f);
          }
        }
      }
      unsigned int h[4], l[4];
      split2(vals[0], vals[1], h[0], l[0]);
      split2(vals[2], vals[3], h[1], l[1]);
      split2(vals[4], vals[5], h[2], l[2]);
      split2(vals[6], vals[7], h[3], l[3]);
      *(uint4*)&Ah[row * LDT + g * 8] = make_uint4(h[0], h[1], h[2], h[3]);
      *(uint4*)&Al[row * LDT + g * 8] = make_uint4(l[0], l[1], l[2], l[3]);
    }
    // ---- stage B
#pragma unroll
    for (int i = 0; i < 4; ++i) {
      int u = tid + i * 256;
      int row = u >> 3, q = u & 7;
      int k = k0 + q * 4;
      int n = n0 + row;
      float4 v = make_float4(0, 0, 0, 0);
      if (n < NC) {
        if (k + 3 < K) v = *(const float4*)(W + (size_t)n * K + k);
        else {
          float* vv = &v.x;
#pragma unroll
          for (int j = 0; j < 4; ++j) if (k + j < K) vv[j] = W[(size_t)n * K + k + j];
        }
      }
      unsigned int h0, l0, h1, l1;
      split2(v.x, v.y, h0, l0);
      split2(v.z, v.w, h1, l1);
      *(uint2*)&Bh[row * LDT + q * 4] = make_uint2(h0, h1);
      *(uint2*)&Bl[row * LDT + q * 4] = make_uint2(l0, l1);
    }
    __syncthreads();

    bf16x8 ah[4], al[4], bh[4], bl[4];
#pragma unroll
    for (int t = 0; t < 4; ++t) {
      int ar = (wm * 64 + t * 16 + lm16) * LDT + quad * 8;
      ah[t] = *(const bf16x8*)&Ah[ar];
      al[t] = *(const bf16x8*)&Al[ar];
      int br = (wn * 64 + t * 16 + lm16) * LDT + quad * 8;
      bh[t] = *(const bf16x8*)&Bh[br];
      bl[t] = *(const bf16x8*)&Bl[br];
    }
#pragma unroll
    for (int mt = 0; mt < 4; ++mt)
#pragma unroll
      for (int nt = 0; nt < 4; ++nt) {
        acc[mt][nt] = __builtin_amdgcn_mfma_f32_16x16x32_bf16(ah[mt], bh[nt], acc[mt][nt], 0, 0, 0);
        acc[mt][nt] = __builtin_amdgcn_mfma_f32_16x16x32_bf16(al[mt], bh[nt], acc[mt][nt], 0, 0, 0);
        acc[mt][nt] = __builtin_amdgcn_mfma_f32_16x16x32_bf16(ah[mt], bl[nt], acc[mt][nt], 0, 0, 0);
      }
    __syncthreads();
  }

  // ---- epilogue: bias, f32 store, column stats
#pragma unroll
  for (int nt = 0; nt < 4; ++nt) {
    int c = n0 + wn * 64 + nt * 16 + lm16;
    bool cv = c < NC;
    float bs = cv ? bias[c] : 0.0f;
    float csum = 0.0f, csq = 0.0f;
#pragma unroll
    for (int mt = 0; mt < 4; ++mt) {
      int rbase = m0 + wm * 64 + mt * 16 + quad * 4;
#pragma unroll
      for (int r = 0; r < 4; ++r) {
        int mm = rbase + r;
        if (mm < M && cv) {
          float v = acc[mt][nt][r] + bs;
          Z2[(size_t)mm * NC + c] = v;
          csum += v; csq += v * v;
        }
      }
    }
    csum += __shfl_down(csum, 16); csum += __shfl_down(csum, 32);
    csq  += __shfl_down(csq, 16);  csq  += __shfl_down(csq, 32);
    if (quad == 0 && cv) {
      atomicAdd(&sumb[c], csum);
      atomicAdd(&sqb[c], csq);
    }
  }
}

// ---------------- host ----------------

extern "C" void kernel_launch(void* const* d_in, const int* in_sizes, int n_in,
                              void* d_out, int out_size, void* d_ws, size_t ws_size,
                              hipStream_t stream) {
  const float* x    = (const float*)d_in[0];
  const float* Wb   = (const float*)d_in[1];   // (L, 300, 9)
  const float* eps  = (const float*)d_in[2];   // (L,)
  const float* W1   = (const float*)d_in[3];   // (L, 600, 300)
  const float* b1   = (const float*)d_in[4];   // (L, 600)
  const float* bn1g = (const float*)d_in[5];
  const float* bn1b = (const float*)d_in[6];
  const float* W2   = (const float*)d_in[7];   // (L, 300, 600)
  const float* b2   = (const float*)d_in[8];   // (L, 300)
  const float* bng  = (const float*)d_in[9];
  const float* bnb  = (const float*)d_in[10];
  const int*   ei   = (const int*)d_in[11];    // (2, E)
  const int*   ea   = (const int*)d_in[12];    // (E, 2)

  float* h = (float*)d_out;                       // N x 300 f32 (aliases z1 bf16 region)
  unsigned short* z1 = (unsigned short*)d_out;    // N x 600 bf16 == exactly out bytes
  float* agg = (float*)d_ws;                      // N x 300 f32 (reused as z2)
  float* z2 = agg;
  float* stats = (float*)d_ws + (size_t)NN * EMBD;
  // stats: [0,600) sum1 | [600,1200) sq1 | [1200,1800) scale1 | [1800,2400) shift1
  //        [2400,2700) sum2 | [2700,3000) sq2 | [3000,3300) scale2 | [3300,3600) shift2

  hipMemcpyAsync(h, x, (size_t)NN * EMBD * sizeof(float), hipMemcpyDeviceToDevice, stream);

  const int n4 = NN * (EMBD / 4);
  const int eltGrid = (n4 + 255) / 256;

  dim3 g1((NN + TM - 1) / TM, (C1D + TN - 1) / TN);   // 782 x 5
  dim3 g2((NN + TM - 1) / TM, (EMBD + TN - 1) / TN);  // 782 x 3

  for (int l = 0; l < NL; ++l) {
    zero_stats_k<<<1, 1024, 0, stream>>>(stats);
    init_agg_k<<<eltGrid, 256, 0, stream>>>(h, eps, l, agg);
    edge_scatter_k<<<NE / 4, 256, 0, stream>>>(h, Wb + (size_t)l * EMBD * 9, ei, ea, agg);
    gemm1_mfma_k<<<g1, 256, 0, stream>>>(
        agg, W1 + (size_t)l * C1D * EMBD, b1 + (size_t)l * C1D, z1, stats + 0, stats + 600);
    finalize_k<<<3, 256, 0, stream>>>(stats + 0, stats + 600, bn1g + (size_t)l * C1D,
                                      bn1b + (size_t)l * C1D, stats + 1200, stats + 1800, C1D);
    gemm2_mfma_k<<<g2, 256, 0, stream>>>(
        z1, stats + 1200, stats + 1800, W2 + (size_t)l * EMBD * C1D, b2 + (size_t)l * EMBD,
        z2, stats + 2400, stats + 2700);
    finalize_k<<<2, 256, 0, stream>>>(stats + 2400, stats + 2700, bng + (size_t)l * EMBD,
                                      bnb + (size_t)l * EMBD, stats + 3000, stats + 3300, EMBD);
    bn_apply_k<<<eltGrid, 256, 0, stream>>>(z2, stats + 3000, stats + 3300, (l < NL - 1) ? 1 : 0, h);
  }
}